// Round 4
// baseline (122.132 us; speedup 1.0000x reference)
//
#include <hip/hip_runtime.h>

// ChamferLoss: B=4, N=M=8192, D=3, fp32. Scalar out.
// VALU-issue-bound. Inner body packs 2 ref points per v_pk_fma_f32 (ref pair
// sourced from SGPRs via uniform s_load -> 1 scalar operand per instr, legal),
// query coords duplicated into VGPR pairs once, min folded via v_min3_f32:
//   per 2 pairs: 3 pk_fma + 1 min3  (~2.2 VALU instr/pair incl rn recompute)
// No LDS at all. Floor if pk_fma is full-rate: ~15 us; half-rate: ~same as r2.

#define BATCH  4
#define NPTS   8192
#define TPB    256
#define QPT    8                      // query points per thread
#define NSLICE 32                     // reference slices
#define NS     (NPTS / NSLICE)        // 256 ref points per block
#define QTILES (NPTS / (TPB * QPT))   // 4  -> grid 1024 blocks (4/CU)
#define TOTALQ (BATCH * NPTS)         // 32768 per direction

typedef float f2 __attribute__((ext_vector_type(2)));

__global__ __launch_bounds__(TPB, 4) void chamfer_dist(const float* __restrict__ xg,
                                                       const float* __restrict__ yg,
                                                       float* __restrict__ partial,
                                                       float* __restrict__ out) {
    const int tid   = threadIdx.x;
    const int qtile = blockIdx.x;
    const int b     = blockIdx.y >> 5;       // / NSLICE
    const int slice = blockIdx.y & (NSLICE - 1);
    const int dir   = blockIdx.z;

    const float* q = dir ? yg : xg;
    const float* r = dir ? xg : yg;

    // zero scalar out (benign identical-value race; reduce runs after via stream order)
    if (tid == 0) out[0] = 0.0f;

    // wave-uniform base for the reference slice -> scalar loads (s_load), SGPR-resident
    const float* rbase = r + (size_t)(b * NPTS + slice * NS) * 3;

    f2 cxx[QPT], cyy[QPT], czz[QPT];
    float qn[QPT], m[QPT];
    const int q0 = qtile * (TPB * QPT);
#pragma unroll
    for (int k = 0; k < QPT; ++k) {
        const int qi = q0 + k * TPB + tid;
        const float* qp = q + (size_t)(b * NPTS + qi) * 3;
        float qx = qp[0], qy = qp[1], qz = qp[2];
        qn[k] = fmaf(qx, qx, fmaf(qy, qy, qz * qz));
        float ax = -2.0f * qx, ay = -2.0f * qy, az = -2.0f * qz;
        cxx[k] = (f2){ax, ax};               // duplicated pairs for packed math
        cyy[k] = (f2){ay, ay};
        czz[k] = (f2){az, az};
        m[k]   = 3.0e38f;
    }

#pragma unroll 2
    for (int g = 0; g < NS / 2; ++g) {       // 2 ref points per iteration
        float x0 = rbase[6 * g + 0], y0 = rbase[6 * g + 1], z0 = rbase[6 * g + 2];
        float x1 = rbase[6 * g + 3], y1 = rbase[6 * g + 4], z1 = rbase[6 * g + 5];
        f2 xx = {x0, x1}, yy = {y0, y1}, zz = {z0, z1};   // SGPR pairs (s_mov repack, SALU)
        f2 rnn = { fmaf(x0, x0, fmaf(y0, y0, z0 * z0)),   // ||r||^2 pair in VGPRs
                   fmaf(x1, x1, fmaf(y1, y1, z1 * z1)) };
#pragma unroll
        for (int k = 0; k < QPT; ++k) {
            f2 t;
            // t = rn - 2*q.r  for both ref points of the pair
            asm("v_pk_fma_f32 %0, %1, %2, %3" : "=v"(t) : "s"(xx), "v"(cxx[k]), "v"(rnn));
            asm("v_pk_fma_f32 %0, %1, %2, %0" : "+v"(t) : "s"(yy), "v"(cyy[k]));
            asm("v_pk_fma_f32 %0, %1, %2, %0" : "+v"(t) : "s"(zz), "v"(czz[k]));
            m[k] = fminf(m[k], fminf(t.x, t.y));          // -> v_min3_f32
        }
    }

    // partial[(dir*BATCH + b)*NSLICE + slice][q] = min + qn
    float* pb = partial + ((size_t)((dir * BATCH + b) * NSLICE + slice)) * NPTS;
#pragma unroll
    for (int k = 0; k < QPT; ++k) {
        const int qi = q0 + k * TPB + tid;
        pb[qi] = m[k] + qn[k];
    }
}

__global__ __launch_bounds__(TPB) void chamfer_reduce(const float* __restrict__ partial,
                                                      float* __restrict__ out) {
    // grid: 64 blocks; each block covers one db (of 8) x 1024 q (thread = float4)
    const int tid = threadIdx.x;
    const int db    = blockIdx.x >> 3;            // [0,8): dir*BATCH + b
    const int chunk = blockIdx.x & 7;             // [0,8)
    const int f4    = chunk * TPB + tid;          // float4 index within NPTS/4

    const float4* p = (const float4*)(partial + (size_t)db * NSLICE * NPTS) + f4;
    float4 v = make_float4(3.0e38f, 3.0e38f, 3.0e38f, 3.0e38f);
    #pragma unroll
    for (int s = 0; s < NSLICE; ++s) {
        float4 t = p[(size_t)s * (NPTS / 4)];     // coalesced 16B loads
        v.x = fminf(v.x, t.x); v.y = fminf(v.y, t.y);
        v.z = fminf(v.z, t.z); v.w = fminf(v.w, t.w);
    }

    float w = (v.x + v.y) + (v.z + v.w);
    #pragma unroll
    for (int off = 32; off > 0; off >>= 1)
        w += __shfl_down(w, off, 64);
    __shared__ float ss[TPB / 64];
    if ((tid & 63) == 0) ss[tid >> 6] = w;
    __syncthreads();
    if (tid == 0) {
        float t = ss[0] + ss[1] + ss[2] + ss[3];
        atomicAdd(out, t * (1.0f / (float)TOTALQ));
    }
}

extern "C" void kernel_launch(void* const* d_in, const int* in_sizes, int n_in,
                              void* d_out, int out_size, void* d_ws, size_t ws_size,
                              hipStream_t stream) {
    const float* x = (const float*)d_in[0];
    const float* y = (const float*)d_in[1];
    float* out = (float*)d_out;
    float* partial = (float*)d_ws;    // 2*BATCH*NSLICE*NPTS*4 = 8 MB

    chamfer_dist<<<dim3(QTILES, BATCH * NSLICE, 2), TPB, 0, stream>>>(x, y, partial, out);
    chamfer_reduce<<<dim3(64), TPB, 0, stream>>>(partial, out);
}

// Round 5
// 111.790 us; speedup vs baseline: 1.0925x; 1.0925x over previous
//
#include <hip/hip_runtime.h>

// ChamferLoss: B=4, N=M=8192, D=3, fp32. Scalar out.
// r2 structure (LDS broadcast tiles, QPT=8, 1024 blocks) + packed fp32:
// ref points pre-paired in LDS, inner body per 2 pairs =
//   3 v_pk_fma_f32 (all-VGPR) + 1 v_min3_f32  -> 2 instr/pair.
// Rate experiment: full-rate pk => ~27us dist; half-rate => neutral vs r2.

#define BATCH  4
#define NPTS   8192
#define TPB    256
#define QPT    8                      // query points per thread
#define NSLICE 32                     // reference slices
#define NS     (NPTS / NSLICE)        // 256 ref points per block
#define NPAIR  (NS / 2)               // 128 packed pairs
#define QTILES (NPTS / (TPB * QPT))   // 4  -> grid 1024 blocks (4/CU)
#define TOTALQ (BATCH * NPTS)         // 32768 per direction

typedef float f2 __attribute__((ext_vector_type(2)));

__global__ __launch_bounds__(TPB) void chamfer_dist(const float* __restrict__ xg,
                                                    const float* __restrict__ yg,
                                                    float* __restrict__ partial,
                                                    float* __restrict__ out) {
    // sA[g] = {x0, x1, y0, y1}   sB[g] = {z0, z1, rn0, rn1}
    __shared__ float4 sA[NPAIR];
    __shared__ float4 sB[NPAIR];

    const int tid   = threadIdx.x;
    const int qtile = blockIdx.x;
    const int b     = blockIdx.y >> 5;           // / NSLICE
    const int slice = blockIdx.y & (NSLICE - 1);
    const int dir   = blockIdx.z;

    const float* q = dir ? yg : xg;
    const float* r = dir ? xg : yg;

    if (tid == 0) out[0] = 0.0f;  // benign identical-value race; reduce runs after

    // stage reference slice into LDS, pair-packed, with ||r||^2
    const float* rbase = r + (size_t)(b * NPTS + slice * NS) * 3;
    {
        const int p = tid;                        // NS == TPB: one point per thread
        const int g = p >> 1, h = p & 1;
        float rx = rbase[p * 3 + 0];
        float ry = rbase[p * 3 + 1];
        float rz = rbase[p * 3 + 2];
        float rn = fmaf(rx, rx, fmaf(ry, ry, rz * rz));
        ((float*)&sA[g])[h]     = rx;
        ((float*)&sA[g])[2 + h] = ry;
        ((float*)&sB[g])[h]     = rz;
        ((float*)&sB[g])[2 + h] = rn;
    }
    __syncthreads();

    f2 cxx[QPT], cyy[QPT], czz[QPT];
    float qn[QPT], m[QPT];
    const int q0 = qtile * (TPB * QPT);
#pragma unroll
    for (int k = 0; k < QPT; ++k) {
        const int qi = q0 + k * TPB + tid;
        const float* qp = q + (size_t)(b * NPTS + qi) * 3;
        float qx = qp[0], qy = qp[1], qz = qp[2];
        qn[k] = fmaf(qx, qx, fmaf(qy, qy, qz * qz));
        float ax = -2.0f * qx, ay = -2.0f * qy, az = -2.0f * qz;
        cxx[k] = (f2){ax, ax};
        cyy[k] = (f2){ay, ay};
        czz[k] = (f2){az, az};
        m[k]   = 3.0e38f;
    }

#pragma unroll 2
    for (int g = 0; g < NPAIR; ++g) {
        // two ds_read_b128 broadcasts (wave-uniform addr, no conflicts)
        const float4 A = sA[g];
        const float4 B = sB[g];
        const f2 xx  = {A.x, A.y};
        const f2 yy  = {A.z, A.w};
        const f2 zz  = {B.x, B.y};
        const f2 rnn = {B.z, B.w};
#pragma unroll
        for (int k = 0; k < QPT; ++k) {
            f2 t;
            // t = rn - 2*q.r for both ref points; all operands VGPR (VOP3P-legal)
            asm("v_pk_fma_f32 %0, %1, %2, %3" : "=v"(t) : "v"(xx), "v"(cxx[k]), "v"(rnn));
            asm("v_pk_fma_f32 %0, %1, %2, %0" : "+v"(t) : "v"(yy), "v"(cyy[k]));
            asm("v_pk_fma_f32 %0, %1, %2, %0" : "+v"(t) : "v"(zz), "v"(czz[k]));
            m[k] = fminf(m[k], fminf(t.x, t.y));  // -> v_min3_f32
        }
    }

    // partial[(dir*BATCH + b)*NSLICE + slice][q] = min + qn
    float* pb = partial + ((size_t)((dir * BATCH + b) * NSLICE + slice)) * NPTS;
#pragma unroll
    for (int k = 0; k < QPT; ++k) {
        const int qi = q0 + k * TPB + tid;
        pb[qi] = m[k] + qn[k];
    }
}

__global__ __launch_bounds__(TPB) void chamfer_reduce(const float* __restrict__ partial,
                                                      float* __restrict__ out) {
    // grid: 64 blocks; each block covers one db (of 8) x 1024 q (thread = float4)
    const int tid   = threadIdx.x;
    const int db    = blockIdx.x >> 3;            // [0,8): dir*BATCH + b
    const int chunk = blockIdx.x & 7;             // [0,8)
    const int f4    = chunk * TPB + tid;          // float4 index within NPTS/4

    const float4* p = (const float4*)(partial + (size_t)db * NSLICE * NPTS) + f4;
    float4 v = make_float4(3.0e38f, 3.0e38f, 3.0e38f, 3.0e38f);
#pragma unroll
    for (int s = 0; s < NSLICE; ++s) {
        float4 t = p[(size_t)s * (NPTS / 4)];     // coalesced 16B loads
        v.x = fminf(v.x, t.x); v.y = fminf(v.y, t.y);
        v.z = fminf(v.z, t.z); v.w = fminf(v.w, t.w);
    }

    float w = (v.x + v.y) + (v.z + v.w);
#pragma unroll
    for (int off = 32; off > 0; off >>= 1)
        w += __shfl_down(w, off, 64);
    __shared__ float ss[TPB / 64];
    if ((tid & 63) == 0) ss[tid >> 6] = w;
    __syncthreads();
    if (tid == 0) {
        float t = ss[0] + ss[1] + ss[2] + ss[3];
        atomicAdd(out, t * (1.0f / (float)TOTALQ));
    }
}

extern "C" void kernel_launch(void* const* d_in, const int* in_sizes, int n_in,
                              void* d_out, int out_size, void* d_ws, size_t ws_size,
                              hipStream_t stream) {
    const float* x = (const float*)d_in[0];
    const float* y = (const float*)d_in[1];
    float* out = (float*)d_out;
    float* partial = (float*)d_ws;    // 2*BATCH*NSLICE*NPTS*4 = 8 MB

    chamfer_dist<<<dim3(QTILES, BATCH * NSLICE, 2), TPB, 0, stream>>>(x, y, partial, out);
    chamfer_reduce<<<dim3(64), TPB, 0, stream>>>(partial, out);
}